// Round 12
// baseline (92.661 us; speedup 1.0000x reference)
//
#include <hip/hip_runtime.h>
#include <hip/hip_bf16.h>
#include <math.h>

// Problem constants
#define B_ROWS 4096
#define N_ROWS 8192
#define D_DIM  1024
#define NTILES 32            // 8192 / 256
#define NSLOT  32            // partial slots per row
#define NPAIRS (NTILES * (NTILES + 1) / 2)  // 528 pairs = 8 * 66
#define NXCD 8
#define POSOFF 16            // tj == ti+16 holds the positives diagonal

#define BM 256
#define BK 128               // i8 elems (bytes) per row per K-tile
#define NT (D_DIM / BK)      // 8 K-tiles
#define BUF_BYTES 65536      // A 32 KB + B 32 KB per ring buffer

typedef __attribute__((ext_vector_type(4))) int i32x4;

__device__ __forceinline__ void load_lds_16B(const void* g, void* l) {
  __builtin_amdgcn_global_load_lds(
      (const __attribute__((address_space(1))) void*)g,
      (__attribute__((address_space(3))) void*)l, 16, 0, 0);
}

#define VMCNT0() asm volatile("s_waitcnt vmcnt(0)" ::: "memory")
#define LGKM0()  asm volatile("s_waitcnt lgkmcnt(0)" ::: "memory")
#define BARRIER() asm volatile("s_barrier" ::: "memory")

// ---------------------------------------------------------------------------
// Kernel 1: wave-per-row L2-normalize + symmetric int8 quantization.
// ---------------------------------------------------------------------------
__global__ __launch_bounds__(256) void normalize_kernel(
    const float* __restrict__ emb_i, const float* __restrict__ emb_j,
    char* __restrict__ zq, float* __restrict__ rowS) {
  const int lane = threadIdx.x & 63;
  const int wave = threadIdx.x >> 6;
  const int row = blockIdx.x * 4 + wave;
  const float* src = (row < B_ROWS) ? (emb_i + (size_t)row * D_DIM)
                                    : (emb_j + (size_t)(row - B_ROWS) * D_DIM);
  const float4* s4 = reinterpret_cast<const float4*>(src);
  float4 v0 = s4[lane], v1 = s4[lane + 64], v2 = s4[lane + 128],
         v3 = s4[lane + 192];

  float ss = v0.x * v0.x + v0.y * v0.y + v0.z * v0.z + v0.w * v0.w +
             v1.x * v1.x + v1.y * v1.y + v1.z * v1.z + v1.w * v1.w +
             v2.x * v2.x + v2.y * v2.y + v2.z * v2.z + v2.w * v2.w +
             v3.x * v3.x + v3.y * v3.y + v3.z * v3.z + v3.w * v3.w;
#pragma unroll
  for (int m = 32; m; m >>= 1) ss += __shfl_xor(ss, m, 64);
  const float scale = 1.0f / fmaxf(sqrtf(ss), 1e-12f);

  float z[16];
  z[0] = v0.x * scale;  z[1] = v0.y * scale;  z[2] = v0.z * scale;
  z[3] = v0.w * scale;  z[4] = v1.x * scale;  z[5] = v1.y * scale;
  z[6] = v1.z * scale;  z[7] = v1.w * scale;  z[8] = v2.x * scale;
  z[9] = v2.y * scale;  z[10] = v2.z * scale; z[11] = v2.w * scale;
  z[12] = v3.x * scale; z[13] = v3.y * scale; z[14] = v3.z * scale;
  z[15] = v3.w * scale;

  float am = 0.0f;
#pragma unroll
  for (int i = 0; i < 16; ++i) am = fmaxf(am, fabsf(z[i]));
#pragma unroll
  for (int m = 32; m; m >>= 1) am = fmaxf(am, __shfl_xor(am, m, 64));
  const float s = am * (1.0f / 127.0f);
  const float inv = (am > 0.0f) ? 127.0f / am : 0.0f;

  char4* dst = reinterpret_cast<char4*>(zq + (size_t)row * D_DIM);
#pragma unroll
  for (int i = 0; i < 4; ++i) {
    char4 pk;
    pk.x = (char)(int)rintf(z[i * 4 + 0] * inv);
    pk.y = (char)(int)rintf(z[i * 4 + 1] * inv);
    pk.z = (char)(int)rintf(z[i * 4 + 2] * inv);
    pk.w = (char)(int)rintf(z[i * 4 + 3] * inv);
    dst[lane + 64 * i] = pk;
  }
  if (lane == 0) rowS[row] = s;
}

// ---------------------------------------------------------------------------
// Kernel 2: fused i8 GEMM + scale + exp + row/col-sum, 256^2 tile pairs,
// 8-phase interleaved schedule (T2 swizzle + T3 phase-split + T5 setprio).
// 512 threads = 8 waves (2M x 4N), wave tile 128x64 -> MFMA:ds_read = 4:1.
// Ring-2 x 64 KB LDS (128 KB, 1 block/CU, 2 waves/SIMD, 256-reg budget:
// acc[8][4] i32x4 = 128 AGPR + ~80 VGPR).
// Staging for tile k+1 fully issued by phase 3 -> tile-end vmcnt(0) covered
// by >= 4 phases of compute.
//
// LDS row = 128 B = 8 16-B slots; logical slot s at physical s ^ (r&7)
// (pre-swizzled global source for linear global_load_lds + XOR'd ds_read;
// residual 2-way conflict = free).
// Frag (16x16x64 i8): lane reads row l15(+16m), 16 B at slot ks*4+l4.
// C/D (16x16, dtype-independent): col = l15, row = l4*4 + reg.
// ---------------------------------------------------------------------------
__global__ __launch_bounds__(512, 2) void simexp_kernel(
    const char* __restrict__ zq, const float* __restrict__ rowS,
    float* __restrict__ partial, float* __restrict__ dn,
    float* __restrict__ pos) {
  __shared__ __align__(16) char ldsbuf[2 * BUF_BYTES];  // 128 KB
  __shared__ float rowAcc[BM];
  __shared__ float colAcc[BM];
  __shared__ float sRow[BM];
  __shared__ float sCol[BM];

  const int tid = threadIdx.x;

  // XCD-chunked bijective swizzle (528 = 8 * 66).
  const int work = (blockIdx.x % NXCD) * (NPAIRS / NXCD) + blockIdx.x / NXCD;

  // triangular decode: work -> (ti, tj), ti <= tj
  int rem = work;
  int ti = 0;
  while (rem >= NTILES - ti) {
    rem -= NTILES - ti;
    ++ti;
  }
  const int tj = ti + rem;
  const bool diag = (ti == tj);
  const int row0 = ti * BM;
  const int m0 = tj * BM;

  if (tid < BM) {
    rowAcc[tid] = 0.0f;
    sRow[tid] = rowS[row0 + tid];
  } else {
    colAcc[tid - BM] = 0.0f;
    sCol[tid - BM] = rowS[m0 + tid - BM];
  }

  const int wave = tid >> 6, lane = tid & 63;
  const int wr = wave >> 2, wc = wave & 3;  // 2x4 wave grid, tile 128x64
  const int l15 = lane & 15, l4 = lane >> 4;

  // ---- staging geometry: thread t -> LDS linear t*16 within an 8 KB round
  // round covers 64 rows; lr = t>>3, phys slot sp = t&7,
  // source logical slot = sp ^ (lr&7)  (rows per round are 64-aligned).
  const int lr = tid >> 3;
  const int sp = tid & 7;
  const int sl = sp ^ (lr & 7);
  const char* gA = zq + (size_t)(row0 + lr) * D_DIM + sl * 16;
  const size_t dB = (size_t)(m0 - row0) * D_DIM;  // A-panel -> B-panel
  const int WD = tid * 16;

  // ---- fragment XOR'd byte-column offsets (same for all frags since
  // frag base rows are 16-aligned -> r&7 == l15&7) ----
  const int xk0 = ((l4 ^ (l15 & 7)) << 4);        // ks=0: slot l4
  const int xk1 = (((4 + l4) ^ (l15 & 7)) << 4);  // ks=1: slot 4+l4

  i32x4 acc[8][4];  // 128 regs, AGPR-backed (4-reg C/D shape)
#pragma unroll
  for (int mi = 0; mi < 8; ++mi)
#pragma unroll
    for (int ni = 0; ni < 4; ++ni) acc[mi][ni] = (i32x4){0, 0, 0, 0};

#define STAGE_ROUND(kk, rr)                                                  \
  load_lds_16B(gA + ((rr) < 4 ? (size_t)0 : dB) + (size_t)((rr)&3) * 65536 + \
                   (size_t)(kk)*BK,                                          \
               ldsbuf + ((kk)&1) * BUF_BYTES + ((rr) < 4 ? 0 : 32768) +      \
                   ((rr)&3) * 8192 + WD)

#define RD_A(mh, ks)                                                   \
  {                                                                    \
    const char* ba_ = slot + (wr * 128 + (mh)*64) * 128;               \
    const int xo_ = (ks) ? xk1 : xk0;                                  \
    af0 = *reinterpret_cast<const i32x4*>(ba_ + (l15) * 128 + xo_);    \
    af1 = *reinterpret_cast<const i32x4*>(ba_ + (l15 + 16) * 128 + xo_); \
    af2 = *reinterpret_cast<const i32x4*>(ba_ + (l15 + 32) * 128 + xo_); \
    af3 = *reinterpret_cast<const i32x4*>(ba_ + (l15 + 48) * 128 + xo_); \
  }

#define RD_B(nh, ks)                                                   \
  {                                                                    \
    const char* bb_ = slot + 32768 + (wc * 64 + (nh)*32) * 128;        \
    const int xo_ = (ks) ? xk1 : xk0;                                  \
    bf0 = *reinterpret_cast<const i32x4*>(bb_ + (l15) * 128 + xo_);    \
    bf1 = *reinterpret_cast<const i32x4*>(bb_ + (l15 + 16) * 128 + xo_); \
  }

#define MFMA8(mh, nh)                                                      \
  __builtin_amdgcn_s_setprio(1);                                           \
  acc[(mh)*4 + 0][(nh)*2 + 0] = __builtin_amdgcn_mfma_i32_16x16x64_i8(     \
      af0, bf0, acc[(mh)*4 + 0][(nh)*2 + 0], 0, 0, 0);                     \
  acc[(mh)*4 + 1][(nh)*2 + 0] = __builtin_amdgcn_mfma_i32_16x16x64_i8(     \
      af1, bf0, acc[(mh)*4 + 1][(nh)*2 + 0], 0, 0, 0);                     \
  acc[(mh)*4 + 2][(nh)*2 + 0] = __builtin_amdgcn_mfma_i32_16x16x64_i8(     \
      af2, bf0, acc[(mh)*4 + 2][(nh)*2 + 0], 0, 0, 0);                     \
  acc[(mh)*4 + 3][(nh)*2 + 0] = __builtin_amdgcn_mfma_i32_16x16x64_i8(     \
      af3, bf0, acc[(mh)*4 + 3][(nh)*2 + 0], 0, 0, 0);                     \
  acc[(mh)*4 + 0][(nh)*2 + 1] = __builtin_amdgcn_mfma_i32_16x16x64_i8(     \
      af0, bf1, acc[(mh)*4 + 0][(nh)*2 + 1], 0, 0, 0);                     \
  acc[(mh)*4 + 1][(nh)*2 + 1] = __builtin_amdgcn_mfma_i32_16x16x64_i8(     \
      af1, bf1, acc[(mh)*4 + 1][(nh)*2 + 1], 0, 0, 0);                     \
  acc[(mh)*4 + 2][(nh)*2 + 1] = __builtin_amdgcn_mfma_i32_16x16x64_i8(     \
      af2, bf1, acc[(mh)*4 + 2][(nh)*2 + 1], 0, 0, 0);                     \
  acc[(mh)*4 + 3][(nh)*2 + 1] = __builtin_amdgcn_mfma_i32_16x16x64_i8(     \
      af3, bf1, acc[(mh)*4 + 3][(nh)*2 + 1], 0, 0, 0);                     \
  __builtin_amdgcn_s_setprio(0);

  // prologue: stage tile 0 fully
  STAGE_ROUND(0, 0); STAGE_ROUND(0, 1); STAGE_ROUND(0, 2); STAGE_ROUND(0, 3);
  STAGE_ROUND(0, 4); STAGE_ROUND(0, 5); STAGE_ROUND(0, 6); STAGE_ROUND(0, 7);
  VMCNT0();
  BARRIER();

  for (int k = 0; k < NT; ++k) {
    const char* slot = ldsbuf + (k & 1) * BUF_BYTES;
    const bool st = (k < NT - 1);
    i32x4 af0, af1, af2, af3, bf0, bf1;

    // phase 0: ks0 mh0 nh0  (+ stage rounds 0,1 of tile k+1)
    RD_A(0, 0); RD_B(0, 0);
    if (st) { STAGE_ROUND(k + 1, 0); STAGE_ROUND(k + 1, 1); }
    BARRIER(); MFMA8(0, 0); BARRIER();
    // phase 1: ks0 mh0 nh1  (+ rounds 2,3)
    RD_B(1, 0);
    if (st) { STAGE_ROUND(k + 1, 2); STAGE_ROUND(k + 1, 3); }
    BARRIER(); MFMA8(0, 1); BARRIER();
    // phase 2: ks0 mh1 nh0  (+ rounds 4,5)
    RD_A(1, 0); RD_B(0, 0);
    if (st) { STAGE_ROUND(k + 1, 4); STAGE_ROUND(k + 1, 5); }
    BARRIER(); MFMA8(1, 0); BARRIER();
    // phase 3: ks0 mh1 nh1  (+ rounds 6,7 -- next tile fully issued)
    RD_B(1, 0);
    if (st) { STAGE_ROUND(k + 1, 6); STAGE_ROUND(k + 1, 7); }
    BARRIER(); MFMA8(1, 1); BARRIER();
    // phase 4: ks1 mh0 nh0
    RD_A(0, 1); RD_B(0, 1);
    BARRIER(); MFMA8(0, 0); BARRIER();
    // phase 5: ks1 mh0 nh1
    RD_B(1, 1);
    BARRIER(); MFMA8(0, 1); BARRIER();
    // phase 6: ks1 mh1 nh0
    RD_A(1, 1); RD_B(0, 1);
    BARRIER(); MFMA8(1, 0); BARRIER();
    // phase 7: ks1 mh1 nh1; tile-end: staging (issued >=4 phases ago) drained
    RD_B(1, 1);
    BARRIER(); MFMA8(1, 1);
    VMCNT0();
    BARRIER();
  }

  // ---- diagonal extraction (PRE-exp, exact int accumulators) ----
  // row rl = wr*128 + mi*16 + l4*4 + j ; col cl = wc*64 + ni*16 + l15
  if (diag || tj == ti + POSOFF) {
    float* dst = diag ? dn : pos;
#pragma unroll
    for (int mi = 0; mi < 8; ++mi) {
#pragma unroll
      for (int ni = 0; ni < 4; ++ni) {
#pragma unroll
        for (int j = 0; j < 4; ++j) {
          const int rl = wr * 128 + mi * 16 + l4 * 4 + j;
          const int cl = wc * 64 + ni * 16 + l15;
          if (rl == cl)
            dst[row0 + rl] = sRow[rl] * sCol[cl] * (float)acc[mi][ni][j];
        }
      }
    }
  }

  // ---- epilogue: scale + exp2 (in place, bitcast) + row/col reductions ----
  const float C2 = 2.8853900817779268f;  // 2*log2(e): exp(2x) = exp2(C2*x)
  const float cc0 = C2 * sCol[wc * 64 + 0 * 16 + l15];
  const float cc1 = C2 * sCol[wc * 64 + 1 * 16 + l15];
  const float cc2 = C2 * sCol[wc * 64 + 2 * 16 + l15];
  const float cc3 = C2 * sCol[wc * 64 + 3 * 16 + l15];

#pragma unroll
  for (int mi = 0; mi < 8; ++mi) {
#pragma unroll
    for (int j = 0; j < 4; ++j) {
      const float srow = sRow[wr * 128 + mi * 16 + l4 * 4 + j];
      acc[mi][0][j] = __float_as_int(exp2f(cc0 * srow * (float)acc[mi][0][j]));
      acc[mi][1][j] = __float_as_int(exp2f(cc1 * srow * (float)acc[mi][1][j]));
      acc[mi][2][j] = __float_as_int(exp2f(cc2 * srow * (float)acc[mi][2][j]));
      acc[mi][3][j] = __float_as_int(exp2f(cc3 * srow * (float)acc[mi][3][j]));
    }
  }

  // row sums: fixed (mi, j, l4) -> in-lane over ni + l15-group reduce
#pragma unroll
  for (int mi = 0; mi < 8; ++mi) {
#pragma unroll
    for (int j = 0; j < 4; ++j) {
      float s = __int_as_float(acc[mi][0][j]) + __int_as_float(acc[mi][1][j]) +
                __int_as_float(acc[mi][2][j]) + __int_as_float(acc[mi][3][j]);
      s += __shfl_xor(s, 1, 64);
      s += __shfl_xor(s, 2, 64);
      s += __shfl_xor(s, 4, 64);
      s += __shfl_xor(s, 8, 64);
      if (l15 == 0) atomicAdd(&rowAcc[wr * 128 + mi * 16 + l4 * 4 + j], s);
    }
  }

  // col sums (off-diagonal only): fixed (ni, l15) -> in-lane over mi,j + l4 fold
  if (!diag) {
#pragma unroll
    for (int ni = 0; ni < 4; ++ni) {
      float s = 0.0f;
#pragma unroll
      for (int mi = 0; mi < 8; ++mi)
#pragma unroll
        for (int j = 0; j < 4; ++j) s += __int_as_float(acc[mi][ni][j]);
      s += __shfl_xor(s, 16, 64);
      s += __shfl_xor(s, 32, 64);
      if (l4 == 0) atomicAdd(&colAcc[wc * 64 + ni * 16 + l15], s);
    }
  }

  LGKM0();  // drain own ds_atomics before the barrier
  BARRIER();
  if (tid < BM) partial[(size_t)(row0 + tid) * NSLOT + tj] = rowAcc[tid];
  if (!diag && tid >= BM && tid < 2 * BM)
    partial[(size_t)(m0 + tid - BM) * NSLOT + ti] = colAcc[tid - BM];
#undef STAGE_ROUND
#undef RD_A
#undef RD_B
#undef MFMA8
}

// ---------------------------------------------------------------------------
// Kernel 3a: per-row loss, block partial sums (32 blocks x 256 threads)
// ---------------------------------------------------------------------------
__global__ void rowloss_kernel(const float* __restrict__ partial,
                               const float* __restrict__ dn,
                               const float* __restrict__ pos,
                               float* __restrict__ blockSum) {
  const int tid = threadIdx.x;
  const int n = blockIdx.x * 256 + tid;  // 0..8191
  const float C2 = 2.8853900817779268f;
  float S = 0.0f;
#pragma unroll
  for (int c = 0; c < NSLOT; ++c) S += partial[(size_t)n * NSLOT + c];
  const float den = S - exp2f(dn[n] * C2);  // remove self-similarity term
  const float p = pos[(n < B_ROWS) ? n : (n - B_ROWS)];
  float acc = -2.0f * p + logf(den);
#pragma unroll
  for (int m = 32; m; m >>= 1) acc += __shfl_xor(acc, m, 64);
  __shared__ float red[4];
  const int wave = tid >> 6, lane = tid & 63;
  if (lane == 0) red[wave] = acc;
  __syncthreads();
  if (tid == 0) blockSum[blockIdx.x] = red[0] + red[1] + red[2] + red[3];
}

// ---------------------------------------------------------------------------
// Kernel 3b: reduce 32 block sums -> scalar loss
// ---------------------------------------------------------------------------
__global__ void final2_kernel(const float* __restrict__ blockSum,
                              float* __restrict__ out) {
  const int tid = threadIdx.x;  // 64
  float v = (tid < 32) ? blockSum[tid] : 0.0f;
#pragma unroll
  for (int m = 32; m; m >>= 1) v += __shfl_xor(v, m, 64);
  if (tid == 0) out[0] = v / (float)N_ROWS;
}

// ---------------------------------------------------------------------------
extern "C" void kernel_launch(void* const* d_in, const int* in_sizes, int n_in,
                              void* d_out, int out_size, void* d_ws,
                              size_t ws_size, hipStream_t stream) {
  const float* emb_i = (const float*)d_in[0];
  const float* emb_j = (const float*)d_in[1];
  float* out = (float*)d_out;

  // workspace layout
  char* zq = (char*)d_ws;                                         // 8 MB i8
  char* p = (char*)d_ws + (size_t)N_ROWS * D_DIM;
  float* partial = (float*)p;                                     // 1 MB
  p += (size_t)N_ROWS * NSLOT * sizeof(float);
  float* dn = (float*)p;                                          // 32 KB
  p += (size_t)N_ROWS * sizeof(float);
  float* rowS = (float*)p;                                        // 32 KB
  p += (size_t)N_ROWS * sizeof(float);
  float* pos = (float*)p;                                         // 16 KB
  p += (size_t)B_ROWS * sizeof(float);
  float* blockSum = (float*)p;                                    // 128 B

  normalize_kernel<<<N_ROWS / 4, 256, 0, stream>>>(emb_i, emb_j, zq, rowS);
  simexp_kernel<<<NPAIRS, 512, 0, stream>>>(zq, rowS, partial, dn, pos);
  rowloss_kernel<<<N_ROWS / 256, 256, 0, stream>>>(partial, dn, pos, blockSum);
  final2_kernel<<<1, 64, 0, stream>>>(blockSum, out);
}